// Round 14
// baseline (407.823 us; speedup 1.0000x reference)
//
#include <hip/hip_runtime.h>
#include <math.h>

// bf16-MFMA decoder, round 14.
// vs r13: (1) gemm128 reverted to BK=32 (r13's BK=64 cut qkv residency 5->2
// blocks/CU, -4us); (2) residual-add fused into wo/ff2 GEMM epilogues so
// ln_kernel reads ONE fp32 stream (saves 8MB read x 6 LNs); (3) attn and
// BK=64 skinny GEMMs unchanged from r13.

#define D_MODEL 512
#define LQ 1024
#define LKK 2048
#define BB 4
#define NL 3
#define KSPLIT 2
#define NROWS 32768   // packed q-rows total = B*8*1024
#define WSZC 262144L  // elems per 512x512 weight matrix

typedef __bf16 bf16;
typedef __bf16 bf16x8 __attribute__((ext_vector_type(8)));
typedef __bf16 bf16x4 __attribute__((ext_vector_type(4)));
typedef float f32x4 __attribute__((ext_vector_type(4)));

__device__ inline f32x4 mfma16(bf16x8 a, bf16x8 b, f32x4 c) {
    return __builtin_amdgcn_mfma_f32_16x16x32_bf16(a, b, c, 0, 0, 0);
}

__device__ inline void gload16(const void* g, void* l) {
    __builtin_amdgcn_global_load_lds(
        (const __attribute__((address_space(1))) void*)g,
        (__attribute__((address_space(3))) void*)l, 16, 0, 0);
}

__device__ inline float fexp2(float x) { return __builtin_amdgcn_exp2f(x); }

// ---------------- cast fp32 -> bf16 ----------------
__global__ __launch_bounds__(256) void cast_kernel(
    const float* __restrict__ in, bf16* __restrict__ out, long n)
{
    long i4 = ((long)blockIdx.x * 256 + threadIdx.x) * 4;
    if (i4 >= n) return;
    float4 v = *(const float4*)(in + i4);
    bf16x4 o;
    o[0] = (bf16)v.x; o[1] = (bf16)v.y; o[2] = (bf16)v.z; o[3] = (bf16)v.w;
    *(bf16x4*)(out + i4) = o;
}

// ---------------- fused copy fp32 + cast bf16 (for h) ----------------
__global__ __launch_bounds__(256) void cast_dual(
    const float* __restrict__ in, float* __restrict__ outf,
    bf16* __restrict__ outb, long n)
{
    long i4 = ((long)blockIdx.x * 256 + threadIdx.x) * 4;
    if (i4 >= n) return;
    float4 v = *(const float4*)(in + i4);
    *(float4*)(outf + i4) = v;
    bf16x4 o;
    o[0] = (bf16)v.x; o[1] = (bf16)v.y; o[2] = (bf16)v.z; o[3] = (bf16)v.w;
    *(bf16x4*)(outb + i4) = o;
}

// ------- ALL weight transpose-casts in one launch: z selects matrix -------
__global__ __launch_bounds__(256) void tcast_all(
    const float* __restrict__ wq, const float* __restrict__ wo,
    const float* __restrict__ f1, const float* __restrict__ f2,
    const float* __restrict__ wk, const float* __restrict__ wv,
    const float* __restrict__ owq, const float* __restrict__ owk,
    bf16* __restrict__ wts, bf16* __restrict__ wtOQ)
{
    __shared__ float t[32][33];
    int z = blockIdx.z;
    const float* src; bf16* dst;
    if (z < 3)       { src = wq  + z * WSZC;        dst = wts + (long)z * WSZC; }
    else if (z < 6)  { src = wo  + (z - 3) * WSZC;  dst = wts + (long)z * WSZC; }
    else if (z < 9)  { src = f1  + (z - 6) * WSZC;  dst = wts + (long)z * WSZC; }
    else if (z < 12) { src = f2  + (z - 9) * WSZC;  dst = wts + (long)z * WSZC; }
    else if (z < 15) { src = wk  + (z - 12) * WSZC; dst = wts + (12 + 2 * (z - 12)) * WSZC; }
    else if (z < 18) { src = wv  + (z - 15) * WSZC; dst = wts + (13 + 2 * (z - 15)) * WSZC; }
    else if (z == 18){ src = owq;                   dst = wtOQ; }
    else             { src = owk;                   dst = wts + 18 * WSZC; }

    int tx = threadIdx.x & 31, ty = threadIdx.x >> 5;
    int x0 = blockIdx.x * 32, y0 = blockIdx.y * 32;
#pragma unroll
    for (int i = 0; i < 4; i++)
        t[ty + 8 * i][tx] = src[(long)(y0 + ty + 8 * i) * 512 + x0 + tx];
    __syncthreads();
#pragma unroll
    for (int i = 0; i < 4; i++)
        dst[(long)(x0 + ty + 8 * i) * 512 + y0 + tx] = (bf16)t[tx][ty + 8 * i];
}

// ------------- mask (int32) -> packed bits -------------
__global__ __launch_bounds__(256) void maskbits_kernel(
    const int* __restrict__ m, unsigned* __restrict__ bits)
{
    long i = (long)blockIdx.x * 256 + threadIdx.x;
    int v = m[i] != 0;
    unsigned long long bal = __ballot(v);
    int lane = threadIdx.x & 63;
    if (lane == 0) bits[i >> 5] = (unsigned)bal;
    else if (lane == 32) bits[i >> 5] = (unsigned)(bal >> 32);
}

// ------------- V transpose: v[(bh)*2048+p][64] -> vt[(bh)*64+d][2048] -------------
__global__ __launch_bounds__(256) void vtrans_kernel(
    const bf16* __restrict__ v, bf16* __restrict__ vt)
{
    __shared__ bf16 t[64][72];
    int bh = blockIdx.y;
    int p0 = blockIdx.x * 64;
    const bf16* vb = v + ((long)bh * 2048 + p0) * 64;
    bf16* vtb = vt + (long)bh * 64 * 2048;
    int tid = threadIdx.x;
#pragma unroll
    for (int it = 0; it < 2; it++) {
        int r = it * 32 + (tid >> 3);
        int c8 = (tid & 7) * 8;
        bf16x8 vv = *(const bf16x8*)(vb + (long)r * 64 + c8);
        *(bf16x8*)&t[r][c8] = vv;
    }
    __syncthreads();
#pragma unroll
    for (int it = 0; it < 2; it++) {
        int d = it * 32 + (tid >> 3);
        int p8 = (tid & 7) * 8;
        bf16x8 ov;
#pragma unroll
        for (int j = 0; j < 8; j++) ov[j] = t[p8 + j][d];
        *(bf16x8*)(vtb + (long)d * 2048 + p0 + p8) = ov;
    }
}

// ------------- 128x64 MFMA GEMM, BK=64, XOR-swizzled LDS (wo/ff1/ff2) -------------
// RES: fp32 residual added in epilogue (fused residual for wo/ff2).
template<int RES, int BIAS, int RELU, int OUT_BF16>
__global__ __launch_bounds__(256) void mfma_gemm(
    const bf16* __restrict__ A, const bf16* __restrict__ Bt,
    const float* __restrict__ bias, const float* __restrict__ res,
    void* __restrict__ Cv, int N, int K)
{
    __shared__ bf16 As[2][8192];   // 128 rows x 64, swizzled
    __shared__ bf16 Bs[2][4096];   // 64 rows x 64, swizzled
    int tid = threadIdx.x;
    int lane = tid & 63, w = tid >> 6;
    int wr = w >> 1, wc = w & 1;
    int g = lane >> 4, c = lane & 15;
    long row0 = (long)blockIdx.y * 128;
    int n0 = blockIdx.x * 64;

    f32x4 acc[4][2];
#pragma unroll
    for (int m = 0; m < 4; m++)
#pragma unroll
        for (int n = 0; n < 2; n++) acc[m][n] = (f32x4){0.f, 0.f, 0.f, 0.f};

    int lr8 = lane >> 3;
    int scol = ((lane & 7) ^ lr8) * 8;    // pre-swizzled source chunk
    int cs = c & 7;

    auto STAGE = [&](int buf, int k0) {
#pragma unroll
        for (int i = 0; i < 4; i++) {
            const bf16* ga = A + (row0 + w * 32 + i * 8 + lr8) * (long)K + k0 + scol;
            gload16(ga, &As[buf][(w * 32 + i * 8) * 64]);
        }
#pragma unroll
        for (int j = 0; j < 2; j++) {
            const bf16* gb = Bt + (long)(n0 + w * 16 + j * 8 + lr8) * K + k0 + scol;
            gload16(gb, &Bs[buf][(w * 16 + j * 8) * 64]);
        }
    };

    STAGE(0, 0);
    __syncthreads();
    int nk = K >> 6;   // BK=64
    for (int it = 0; it < nk; ++it) {
        int cur = it & 1;
        if (it + 1 < nk) STAGE(cur ^ 1, (it + 1) << 6);
#pragma unroll
        for (int kk = 0; kk < 2; kk++) {
            int ch = ((kk << 2) + g);
            bf16x8 af[4], bfr[2];
#pragma unroll
            for (int m = 0; m < 4; m++)
                af[m] = *(const bf16x8*)
                    &As[cur][(wr * 64 + m * 16 + c) * 64 + ((ch ^ cs) << 3)];
#pragma unroll
            for (int n = 0; n < 2; n++)
                bfr[n] = *(const bf16x8*)
                    &Bs[cur][(wc * 32 + n * 16 + c) * 64 + ((ch ^ cs) << 3)];
#pragma unroll
            for (int m = 0; m < 4; m++)
#pragma unroll
                for (int n = 0; n < 2; n++)
                    acc[m][n] = mfma16(af[m], bfr[n], acc[m][n]);
        }
        __syncthreads();
    }

    float bv[2] = {0.f, 0.f};
    if (BIAS) {
#pragma unroll
        for (int n = 0; n < 2; n++) bv[n] = bias[n0 + wc * 32 + n * 16 + c];
    }
    float* Cf = (float*)Cv;
    bf16* Cb = (bf16*)Cv;
#pragma unroll
    for (int m = 0; m < 4; m++)
#pragma unroll
        for (int n = 0; n < 2; n++)
#pragma unroll
            for (int j = 0; j < 4; j++) {
                long row = row0 + wr * 64 + m * 16 + g * 4 + j;
                int col = n0 + wc * 32 + n * 16 + c;
                float v = acc[m][n][j];
                if (BIAS) v += bv[n];
                if (RELU) v = fmaxf(v, 0.f);
                if (RES) v += res[row * N + col];
                if (OUT_BF16) Cb[row * N + col] = (bf16)v;
                else Cf[row * N + col] = v;
            }
}

// ------------- 128x128 MFMA GEMM core (double-buffered, BK=32) -------------
template<int OUT_BF16>
__device__ inline void gemm128_body(
    const bf16* __restrict__ Ab, const bf16* __restrict__ Bb,
    void* __restrict__ Cv, int N, int K, float scale,
    long row0, int n0)
{
    __shared__ bf16 As[2][4096];
    __shared__ bf16 Bs[2][4096];
    int tid = threadIdx.x;
    int lane = tid & 63, w = tid >> 6;
    int wr = w >> 1, wc = w & 1;
    int g = lane >> 4, c = lane & 15;

    f32x4 acc[4][4];
#pragma unroll
    for (int m = 0; m < 4; m++)
#pragma unroll
        for (int n = 0; n < 4; n++) acc[m][n] = (f32x4){0.f, 0.f, 0.f, 0.f};

    int lr4 = lane >> 2, lc8 = (lane & 3) * 8;
    auto STAGE = [&](int buf, int k0) {
        const bf16* ga = Ab + (row0 + w * 16 + lr4) * (long)K + k0 + lc8;
        gload16(ga, &As[buf][(w * 16) * 32]);
        gload16(ga + (long)64 * K, &As[buf][(w * 16 + 64) * 32]);
        const bf16* gb = Bb + (long)(n0 + w * 16 + lr4) * K + k0 + lc8;
        gload16(gb, &Bs[buf][(w * 16) * 32]);
        gload16(gb + (long)64 * K, &Bs[buf][(w * 16 + 64) * 32]);
    };

    STAGE(0, 0);
    __syncthreads();
    int nk = K >> 5;
    for (int it = 0; it < nk; ++it) {
        int cur = it & 1;
        if (it + 1 < nk) STAGE(cur ^ 1, (it + 1) << 5);
        bf16x8 af[4], bfr[4];
#pragma unroll
        for (int m = 0; m < 4; m++)
            af[m] = *(const bf16x8*)&As[cur][(wr * 64 + m * 16 + c) * 32 + g * 8];
#pragma unroll
        for (int n = 0; n < 4; n++)
            bfr[n] = *(const bf16x8*)&Bs[cur][(wc * 64 + n * 16 + c) * 32 + g * 8];
#pragma unroll
        for (int m = 0; m < 4; m++)
#pragma unroll
            for (int n = 0; n < 4; n++)
                acc[m][n] = mfma16(af[m], bfr[n], acc[m][n]);
        __syncthreads();
    }

    float* Cf = (float*)Cv;
    bf16* Cb = (bf16*)Cv;
#pragma unroll
    for (int m = 0; m < 4; m++)
#pragma unroll
        for (int n = 0; n < 4; n++)
#pragma unroll
            for (int j = 0; j < 4; j++) {
                long row = row0 + wr * 64 + m * 16 + g * 4 + j;
                int col = n0 + wc * 64 + n * 16 + c;
                float v = acc[m][n][j] * scale;
                if (OUT_BF16) Cb[row * N + col] = (bf16)v;
                else Cf[row * N + col] = v;
            }
}

// batched final-scores GEMM (fp32 out, scaled)
__global__ __launch_bounds__(256) void mfma_gemm128(
    const bf16* __restrict__ A, const bf16* __restrict__ Bt,
    float* __restrict__ Cv, int N, int K, float scale,
    long sA, long sB, long sC)
{
    long z = blockIdx.z;
    gemm128_body<0>(A + z * sA, Bt + z * sB, Cv + z * sC, N, K, scale,
                    (long)blockIdx.y * 128, blockIdx.x * 128);
}

// Q/K/V (z=3) or qf/kf (z=2) batched projections, 128x128 tiles.
__global__ __launch_bounds__(256) void qkv_gemm(
    const bf16* __restrict__ Ah, const bf16* __restrict__ Ax,
    const bf16* __restrict__ B0, const bf16* __restrict__ B1,
    const bf16* __restrict__ B2,
    bf16* __restrict__ C0, bf16* __restrict__ C1, bf16* __restrict__ C2,
    float scale0)
{
    int z = blockIdx.z;
    if (z == 0 && blockIdx.y >= 32) return;
    const bf16* A = z ? Ax : Ah;
    const bf16* Bt = (z == 0) ? B0 : (z == 1 ? B1 : B2);
    bf16* C = (z == 0) ? C0 : (z == 1 ? C1 : C2);
    gemm128_body<1>(A, Bt, C, 512, 512, z == 0 ? scale0 : 1.f,
                    (long)blockIdx.y * 128, blockIdx.x * 128);
}

// ------------- MFMA flash attention: 8 waves x 16 q = 128 q/block -------------
// Grid 512 flat = (8 qb, 32 bh, 2 sp) XCD-chunked. Q pre-scaled 0.125*log2e.
__global__ __launch_bounds__(512, 4) void attn_mfma(
    const bf16* __restrict__ QP, const bf16* __restrict__ KP,
    const bf16* __restrict__ Vt, const unsigned* __restrict__ bits,
    bf16* __restrict__ Opart, float* __restrict__ Mpart,
    float* __restrict__ Lpart)
{
    __shared__ bf16 Kls[2][4096];      // [buf][64 keys x 64 d], swizzled
    __shared__ bf16 Vls[2][4096];      // [buf][64 d x 64 keys], swizzled
    __shared__ bf16 Pl[8][1024];       // per-wave P [q=c][64 keys], XOR-swizzled

    int tid = threadIdx.x;
    int lane = tid & 63, wv = tid >> 6;   // 8 waves
    int g = lane >> 4, c = lane & 15;

    int flat = blockIdx.x;                          // 512 blocks
    int logical = (flat & 7) * 64 + (flat >> 3);    // XCD-chunked
    int bh = logical >> 4;
    int rr = logical & 15;
    int sp = rr >> 3;
    int q0 = (rr & 7) * 128 + wv * 16;
    int b = bh >> 3;

    long qrow0 = (long)bh * 1024 + q0;
    long krow0 = (long)bh * 2048 + (long)sp * 1024;
    const bf16* vtb = Vt + (long)bh * 131072 + (long)sp * 1024;
    const unsigned* bitrow = bits + ((long)b * 1024 + q0 + c) * 64 + sp * 32;

    int lr = lane >> 3, lc = lane & 7;
    int scol = (lc ^ lr) * 8;                       // pre-swizzled src col
    int cs = c & 7;

    bf16x8 qa[2];
#pragma unroll
    for (int hh = 0; hh < 2; hh++)
        qa[hh] = *(const bf16x8*)(QP + (qrow0 + c) * 64 + hh * 32 + g * 8);

    f32x4 o_acc[4];
#pragma unroll
    for (int ot = 0; ot < 4; ot++) o_acc[ot] = (f32x4){0.f, 0.f, 0.f, 0.f};
    float m_r = -1e30f, l_r = 0.f;     // l_r lane-local (exact: fct row-uniform)

    {
        const bf16* sk = KP + (krow0 + wv * 8 + lr) * 64 + scol;
        gload16(sk, &Kls[0][(wv * 8) * 64]);
        const bf16* sv = vtb + (long)(wv * 8 + lr) * 2048 + scol;
        gload16(sv, &Vls[0][(wv * 8) * 64]);
    }
    uint2 wp_nxt = *(const uint2*)(bitrow);
    __syncthreads();

    const int NT = LKK / KSPLIT / 64;   // 16
    for (int kt = 0; kt < NT; kt++) {
        int cur = kt & 1;
        if (kt + 1 < NT) {
            int kn = (kt + 1) * 64;
            const bf16* sk = KP + (krow0 + kn + wv * 8 + lr) * 64 + scol;
            gload16(sk, &Kls[cur ^ 1][(wv * 8) * 64]);
            const bf16* sv = vtb + (long)(wv * 8 + lr) * 2048 + kn + scol;
            gload16(sv, &Vls[cur ^ 1][(wv * 8) * 64]);
        }
        uint2 wp = wp_nxt;
        if (kt + 1 < NT) wp_nxt = *(const uint2*)(bitrow + (kt + 1) * 2);

        // S^T = K Q^T from LDS (swizzled read); already log2-domain
        const char* kls = (const char*)&Kls[cur][0];
        f32x4 s[4];
        __builtin_amdgcn_s_setprio(1);
#pragma unroll
        for (int mt = 0; mt < 4; mt++) {
            bf16x8 ka0 = *(const bf16x8*)(kls + (mt * 16 + c) * 128 + ((g ^ cs) << 4));
            bf16x8 ka1 = *(const bf16x8*)(kls + (mt * 16 + c) * 128 + (((4 + g) ^ cs) << 4));
            s[mt] = mfma16(ka0, qa[0], (f32x4){0.f, 0.f, 0.f, 0.f});
            s[mt] = mfma16(ka1, qa[1], s[mt]);
        }
        __builtin_amdgcn_s_setprio(0);

        // mask: one runtime shift per mt, then constant-shift bit tests
#pragma unroll
        for (int mt = 0; mt < 4; mt++) {
            unsigned wm = ((mt < 2) ? wp.x : wp.y) >> ((mt & 1) * 16 + 4 * g);
#pragma unroll
            for (int j = 0; j < 4; j++)
                if ((wm >> j) & 1) s[mt][j] = -1e30f;
        }

        // online softmax (log2 domain): conditional row-max + defer-max
        float mxl = -1e30f;
#pragma unroll
        for (int mt = 0; mt < 4; mt++)
            mxl = fmaxf(mxl, fmaxf(fmaxf(s[mt][0], s[mt][1]),
                                   fmaxf(s[mt][2], s[mt][3])));

        float fct = 1.f;
        if (__any(mxl > m_r + 11.5415f)) {
            float mx = fmaxf(mxl, __shfl_xor(mxl, 16, 64));
            mx = fmaxf(mx, __shfl_xor(mx, 32, 64));
            float mnew = fmaxf(m_r, mx);
            fct = fexp2(m_r - mnew);
            m_r = mnew;
            float fq[4];
#pragma unroll
            for (int j = 0; j < 4; j++)
                fq[j] = __shfl(fct, (lane & 48) | (4 * g + j), 64);
#pragma unroll
            for (int ot = 0; ot < 4; ot++)
#pragma unroll
                for (int j = 0; j < 4; j++) o_acc[ot][j] *= fq[j];
        }

        float sum = 0.f;
#pragma unroll
        for (int mt = 0; mt < 4; mt++)
#pragma unroll
            for (int j = 0; j < 4; j++) {
                float p = fexp2(s[mt][j] - m_r);
                s[mt][j] = p;
                sum += p;
            }
        l_r = l_r * fct + sum;   // lane-local; reduced once at end

        // P -> per-wave LDS, XOR-swizzled
        char* plb = (char*)&Pl[wv][0];
#pragma unroll
        for (int mt = 0; mt < 4; mt++) {
            bf16x4 pk;
#pragma unroll
            for (int j = 0; j < 4; j++) pk[j] = (bf16)s[mt][j];
            int wch = (mt * 2 + (g >> 1)) ^ cs;
            *(bf16x4*)(plb + c * 128 + (wch << 4) + (g & 1) * 8) = pk;
        }

        // PV
        const char* vls = (const char*)&Vls[cur][0];
        __builtin_amdgcn_s_setprio(1);
#pragma unroll
        for (int kh = 0; kh < 2; kh++) {
            bf16x8 pa = *(const bf16x8*)(plb + c * 128 + ((((kh << 2) + g) ^ cs) << 4));
#pragma unroll
            for (int ot = 0; ot < 4; ot++) {
                bf16x8 vbf = *(const bf16x8*)
                    (vls + (ot * 16 + c) * 128 + ((((kh << 2) + g) ^ cs) << 4));
                o_acc[ot] = mfma16(pa, vbf, o_acc[ot]);
            }
        }
        __builtin_amdgcn_s_setprio(0);
        __syncthreads();
    }

    // final l_r row-reduction
    l_r += __shfl_xor(l_r, 16, 64);
    l_r += __shfl_xor(l_r, 32, 64);

    long ob = ((long)sp * NROWS + qrow0) * 64;
#pragma unroll
    for (int ot = 0; ot < 4; ot++)
#pragma unroll
        for (int j = 0; j < 4; j++)
            Opart[ob + (long)(4 * g + j) * 64 + ot * 16 + c] = (bf16)o_acc[ot][j];
    if (g == 0) {
        Mpart[(long)sp * NROWS + qrow0 + c] = m_r;
        Lpart[(long)sp * NROWS + qrow0 + c] = l_r;
    }
}

// ------------- combine k-split partials (log2-domain stats) -------------
__global__ __launch_bounds__(256) void attn_combine(
    const bf16* __restrict__ Op, const float* __restrict__ Mp,
    const float* __restrict__ Lp, bf16* __restrict__ O)
{
    long idx = (long)blockIdx.x * 256 + threadIdx.x;
    long row = idx >> 6;
    float m0 = Mp[row], m1 = Mp[NROWS + row];
    float l0 = Lp[row], l1 = Lp[NROWS + row];
    float mm = fmaxf(m0, m1);
    float e0 = fexp2(m0 - mm), e1 = fexp2(m1 - mm);
    float inv = 1.f / (l0 * e0 + l1 * e1);
    float o = ((float)Op[idx] * e0 + (float)Op[(long)NROWS * 64 + idx] * e1) * inv;
    O[idx] = (bf16)o;
}

// ------------- LN of single pre-accumulated stream -------------
__global__ __launch_bounds__(256) void ln_kernel(
    const float* __restrict__ y,
    const float* __restrict__ g, const float* __restrict__ bb,
    float* __restrict__ outf, bf16* __restrict__ outb)
{
    int wave = threadIdx.x >> 6, lane = threadIdx.x & 63;
    long row = (long)blockIdx.x * 4 + wave;
    const float* yp = y + row * D_MODEL;
    float v[8];
    float s = 0.f, sq = 0.f;
#pragma unroll
    for (int j = 0; j < 8; j++) {
        int col = lane + 64 * j;
        v[j] = yp[col];
        s += v[j]; sq += v[j] * v[j];
    }
#pragma unroll
    for (int o = 32; o > 0; o >>= 1) {
        s += __shfl_down(s, o, 64);
        sq += __shfl_down(sq, o, 64);
    }
    s = __shfl(s, 0, 64);
    sq = __shfl(sq, 0, 64);
    float mean = s * (1.f / 512.f);
    float var = sq * (1.f / 512.f) - mean * mean;
    float rstd = rsqrtf(fmaxf(var, 0.f) + 1e-5f);
    float* opf = outf + row * D_MODEL;
    bf16* opb = outb + row * D_MODEL;
#pragma unroll
    for (int j = 0; j < 8; j++) {
        int col = lane + 64 * j;
        float o = (v[j] - mean) * rstd * g[col] + bb[col];
        opf[col] = o;
        opb[col] = (bf16)o;
    }
}

extern "C" void kernel_launch(void* const* d_in, const int* in_sizes, int n_in,
                              void* d_out, int out_size, void* d_ws, size_t ws_size,
                              hipStream_t stream)
{
    const float* x    = (const float*)d_in[0];
    const float* hin  = (const float*)d_in[1];
    const int*   mask = (const int*)d_in[2];
    const float* wq   = (const float*)d_in[3];
    const float* wk   = (const float*)d_in[4];
    const float* wv   = (const float*)d_in[5];
    const float* wo   = (const float*)d_in[6];
    const float* ffw1 = (const float*)d_in[7];
    const float* ffb1 = (const float*)d_in[8];
    const float* ffw2 = (const float*)d_in[9];
    const float* ffb2 = (const float*)d_in[10];
    const float* g1   = (const float*)d_in[11];
    const float* be1  = (const float*)d_in[12];
    const float* g2   = (const float*)d_in[13];
    const float* be2  = (const float*)d_in[14];
    const float* out_wq = (const float*)d_in[15];
    const float* out_wk = (const float*)d_in[16];
    float* out = (float*)d_out;

    const long NQ = (long)BB * LQ;   // 4096
    const long NK = (long)BB * LKK;  // 8192

    // workspace layout (bytes). SH region time-shares y_f / V-plane / Opart.
    char* W = (char*)d_ws;
    float* h_f  = (float*)(W);                      // 8 MB (fp32 residual)
    char*  SH   = W + 8388608;                      // 8 MB shared region
    float* y_f  = (float*)SH;
    bf16*  v_pl = (bf16*)SH;
    bf16*  opart= (bf16*)SH;
    bf16*  h_b  = (bf16*)(W + 16777216);            // 4 MB
    bf16*  x_b  = (bf16*)(W + 20971520);            // 8 MB
    bf16*  q_b  = (bf16*)(W + 29360128);            // 4 MB
    bf16*  a_b  = (bf16*)(W + 33554432);            // 4 MB
    bf16*  k_pl = (bf16*)(W + 37748736);            // 8 MB
    bf16*  vt   = (bf16*)(W + 46137344);            // 8 MB
    bf16*  wts  = (bf16*)(W + 54525952);            // 19 matrices (9.5 MB)
    bf16*  wtOQ = wts + 19 * WSZC;                  // +0.5 MB
    unsigned* mb = (unsigned*)(W + 65011712);       // 1 MB
    float* Mpart = (float*)(W + 66060288);          // 256 KB
    float* Lpart = (float*)(W + 66322432);          // 256 KB

    dim3 blk(256);
    dim3 blk512(512);

    // preprocessing
    cast_kernel<<<dim3((NK * D_MODEL / 4 + 255) / 256), blk, 0, stream>>>(x, x_b, NK * D_MODEL);
    cast_dual<<<dim3((NQ * D_MODEL / 4 + 255) / 256), blk, 0, stream>>>(hin, h_f, h_b, NQ * D_MODEL);
    tcast_all<<<dim3(16, 16, 20), blk, 0, stream>>>(
        wq, wo, ffw1, ffw2, wk, wv, out_wq, out_wk, wts, wtOQ);
    maskbits_kernel<<<dim3(32768), blk, 0, stream>>>(mask, mb);

    dim3 gq(8, 32, 1);           // 4096 x 512 (128x64, BK=64)
    dim3 gqkv(4, 64, 3);         // z: Q(4096) / K(8192) / V(8192), 128x128 BK=32
    dim3 gvt(32, 32);
    dim3 ga(512);                // flat, XCD-swizzled inside; 512-thread blocks
    dim3 gc(NROWS * 64 / 256);

    const float C2 = 0.1803368801111243f;   // 0.125 * log2(e)

    for (int i = 0; i < NL; i++) {
        qkv_gemm<<<gqkv, blk, 0, stream>>>(h_b, x_b,
            wts + i * WSZC, wts + (12 + 2 * i) * WSZC, wts + (13 + 2 * i) * WSZC,
            q_b, k_pl, v_pl, C2);
        vtrans_kernel<<<gvt, blk, 0, stream>>>(v_pl, vt);

        attn_mfma<<<ga, blk512, 0, stream>>>(q_b, k_pl, vt, mb, opart, Mpart, Lpart);
        attn_combine<<<gc, blk, 0, stream>>>(opart, Mpart, Lpart, a_b);

        // wo GEMM with fused residual (+h_f), fp32 out -> y_f
        mfma_gemm<1,0,0,0><<<gq, blk, 0, stream>>>(a_b, wts + (3 + i) * WSZC,
            nullptr, h_f, y_f, 512, 512);
        ln_kernel<<<dim3(NQ / 4), blk, 0, stream>>>(y_f,
            g1 + i * D_MODEL, be1 + i * D_MODEL, h_f, h_b);

        // ff1: bias+relu, bf16 out
        mfma_gemm<0,1,1,1><<<gq, blk, 0, stream>>>(h_b, wts + (6 + i) * WSZC,
            ffb1 + i * D_MODEL, nullptr, q_b, 512, 512);
        // ff2: bias + fused residual (+h_f = LN1 out), fp32 out -> y_f
        mfma_gemm<1,1,0,0><<<gq, blk, 0, stream>>>(q_b, wts + (9 + i) * WSZC,
            ffb2 + i * D_MODEL, h_f, y_f, 512, 512);
        ln_kernel<<<dim3(NQ / 4), blk, 0, stream>>>(y_f,
            g2 + i * D_MODEL, be2 + i * D_MODEL, h_f, h_b);
    }

    // final: qf = h@out_wq (z=0, unscaled), kf = x@out_wk (z=1)
    dim3 gqk(4, 64, 2);
    qkv_gemm<<<gqk, blk, 0, stream>>>(h_b, x_b,
        wtOQ, wts + 18 * WSZC, wts + 18 * WSZC, q_b, k_pl, k_pl, 1.f);

    dim3 gf(LKK / 128, LQ / 128, BB);
    mfma_gemm128<<<gf, blk, 0, stream>>>(q_b, k_pl, out,
        LKK, 512, 0.04419417382415922f,
        (long)LQ * 512, (long)LKK * 512, (long)LQ * LKK);
}

// Round 15
// 392.451 us; speedup vs baseline: 1.0392x; 1.0392x over previous
//
#include <hip/hip_runtime.h>
#include <math.h>

// bf16-MFMA decoder, round 15 = best-known config (r12) restored:
// - gemm128 BK=32 (r13's BK=64 cut qkv residency: -4us)
// - NO residual fusion (r14's epilogue res-read serialized: -8us)
// - two-input ln_kernel (res + y)
// - attn: r13 variant (8 waves x 16q, lane-local l_r, cheap mask) -- measured
//   equal-or-better than r12's attn
// + one isolated tweak: attn_combine vectorized bf16x4 (grid 8192->2048).

#define D_MODEL 512
#define LQ 1024
#define LKK 2048
#define BB 4
#define NL 3
#define KSPLIT 2
#define NROWS 32768   // packed q-rows total = B*8*1024
#define WSZC 262144L  // elems per 512x512 weight matrix

typedef __bf16 bf16;
typedef __bf16 bf16x8 __attribute__((ext_vector_type(8)));
typedef __bf16 bf16x4 __attribute__((ext_vector_type(4)));
typedef float f32x4 __attribute__((ext_vector_type(4)));

__device__ inline f32x4 mfma16(bf16x8 a, bf16x8 b, f32x4 c) {
    return __builtin_amdgcn_mfma_f32_16x16x32_bf16(a, b, c, 0, 0, 0);
}

__device__ inline void gload16(const void* g, void* l) {
    __builtin_amdgcn_global_load_lds(
        (const __attribute__((address_space(1))) void*)g,
        (__attribute__((address_space(3))) void*)l, 16, 0, 0);
}

__device__ inline float fexp2(float x) { return __builtin_amdgcn_exp2f(x); }

// ---------------- cast fp32 -> bf16 ----------------
__global__ __launch_bounds__(256) void cast_kernel(
    const float* __restrict__ in, bf16* __restrict__ out, long n)
{
    long i4 = ((long)blockIdx.x * 256 + threadIdx.x) * 4;
    if (i4 >= n) return;
    float4 v = *(const float4*)(in + i4);
    bf16x4 o;
    o[0] = (bf16)v.x; o[1] = (bf16)v.y; o[2] = (bf16)v.z; o[3] = (bf16)v.w;
    *(bf16x4*)(out + i4) = o;
}

// ---------------- fused copy fp32 + cast bf16 (for h) ----------------
__global__ __launch_bounds__(256) void cast_dual(
    const float* __restrict__ in, float* __restrict__ outf,
    bf16* __restrict__ outb, long n)
{
    long i4 = ((long)blockIdx.x * 256 + threadIdx.x) * 4;
    if (i4 >= n) return;
    float4 v = *(const float4*)(in + i4);
    *(float4*)(outf + i4) = v;
    bf16x4 o;
    o[0] = (bf16)v.x; o[1] = (bf16)v.y; o[2] = (bf16)v.z; o[3] = (bf16)v.w;
    *(bf16x4*)(outb + i4) = o;
}

// ------- ALL weight transpose-casts in one launch: z selects matrix -------
__global__ __launch_bounds__(256) void tcast_all(
    const float* __restrict__ wq, const float* __restrict__ wo,
    const float* __restrict__ f1, const float* __restrict__ f2,
    const float* __restrict__ wk, const float* __restrict__ wv,
    const float* __restrict__ owq, const float* __restrict__ owk,
    bf16* __restrict__ wts, bf16* __restrict__ wtOQ)
{
    __shared__ float t[32][33];
    int z = blockIdx.z;
    const float* src; bf16* dst;
    if (z < 3)       { src = wq  + z * WSZC;        dst = wts + (long)z * WSZC; }
    else if (z < 6)  { src = wo  + (z - 3) * WSZC;  dst = wts + (long)z * WSZC; }
    else if (z < 9)  { src = f1  + (z - 6) * WSZC;  dst = wts + (long)z * WSZC; }
    else if (z < 12) { src = f2  + (z - 9) * WSZC;  dst = wts + (long)z * WSZC; }
    else if (z < 15) { src = wk  + (z - 12) * WSZC; dst = wts + (12 + 2 * (z - 12)) * WSZC; }
    else if (z < 18) { src = wv  + (z - 15) * WSZC; dst = wts + (13 + 2 * (z - 15)) * WSZC; }
    else if (z == 18){ src = owq;                   dst = wtOQ; }
    else             { src = owk;                   dst = wts + 18 * WSZC; }

    int tx = threadIdx.x & 31, ty = threadIdx.x >> 5;
    int x0 = blockIdx.x * 32, y0 = blockIdx.y * 32;
#pragma unroll
    for (int i = 0; i < 4; i++)
        t[ty + 8 * i][tx] = src[(long)(y0 + ty + 8 * i) * 512 + x0 + tx];
    __syncthreads();
#pragma unroll
    for (int i = 0; i < 4; i++)
        dst[(long)(x0 + ty + 8 * i) * 512 + y0 + tx] = (bf16)t[tx][ty + 8 * i];
}

// ------------- mask (int32) -> packed bits -------------
__global__ __launch_bounds__(256) void maskbits_kernel(
    const int* __restrict__ m, unsigned* __restrict__ bits)
{
    long i = (long)blockIdx.x * 256 + threadIdx.x;
    int v = m[i] != 0;
    unsigned long long bal = __ballot(v);
    int lane = threadIdx.x & 63;
    if (lane == 0) bits[i >> 5] = (unsigned)bal;
    else if (lane == 32) bits[i >> 5] = (unsigned)(bal >> 32);
}

// ------------- V transpose: v[(bh)*2048+p][64] -> vt[(bh)*64+d][2048] -------------
__global__ __launch_bounds__(256) void vtrans_kernel(
    const bf16* __restrict__ v, bf16* __restrict__ vt)
{
    __shared__ bf16 t[64][72];
    int bh = blockIdx.y;
    int p0 = blockIdx.x * 64;
    const bf16* vb = v + ((long)bh * 2048 + p0) * 64;
    bf16* vtb = vt + (long)bh * 64 * 2048;
    int tid = threadIdx.x;
#pragma unroll
    for (int it = 0; it < 2; it++) {
        int r = it * 32 + (tid >> 3);
        int c8 = (tid & 7) * 8;
        bf16x8 vv = *(const bf16x8*)(vb + (long)r * 64 + c8);
        *(bf16x8*)&t[r][c8] = vv;
    }
    __syncthreads();
#pragma unroll
    for (int it = 0; it < 2; it++) {
        int d = it * 32 + (tid >> 3);
        int p8 = (tid & 7) * 8;
        bf16x8 ov;
#pragma unroll
        for (int j = 0; j < 8; j++) ov[j] = t[p8 + j][d];
        *(bf16x8*)(vtb + (long)d * 2048 + p0 + p8) = ov;
    }
}

// ------------- 128x64 MFMA GEMM, BK=64, XOR-swizzled LDS (wo/ff1/ff2) -------------
template<int BIAS, int RELU, int OUT_BF16>
__global__ __launch_bounds__(256) void mfma_gemm(
    const bf16* __restrict__ A, const bf16* __restrict__ Bt,
    const float* __restrict__ bias, void* __restrict__ Cv,
    int N, int K)
{
    __shared__ bf16 As[2][8192];   // 128 rows x 64, swizzled
    __shared__ bf16 Bs[2][4096];   // 64 rows x 64, swizzled
    int tid = threadIdx.x;
    int lane = tid & 63, w = tid >> 6;
    int wr = w >> 1, wc = w & 1;
    int g = lane >> 4, c = lane & 15;
    long row0 = (long)blockIdx.y * 128;
    int n0 = blockIdx.x * 64;

    f32x4 acc[4][2];
#pragma unroll
    for (int m = 0; m < 4; m++)
#pragma unroll
        for (int n = 0; n < 2; n++) acc[m][n] = (f32x4){0.f, 0.f, 0.f, 0.f};

    int lr8 = lane >> 3;
    int scol = ((lane & 7) ^ lr8) * 8;    // pre-swizzled source chunk
    int cs = c & 7;

    auto STAGE = [&](int buf, int k0) {
#pragma unroll
        for (int i = 0; i < 4; i++) {
            const bf16* ga = A + (row0 + w * 32 + i * 8 + lr8) * (long)K + k0 + scol;
            gload16(ga, &As[buf][(w * 32 + i * 8) * 64]);
        }
#pragma unroll
        for (int j = 0; j < 2; j++) {
            const bf16* gb = Bt + (long)(n0 + w * 16 + j * 8 + lr8) * K + k0 + scol;
            gload16(gb, &Bs[buf][(w * 16 + j * 8) * 64]);
        }
    };

    STAGE(0, 0);
    __syncthreads();
    int nk = K >> 6;   // BK=64
    for (int it = 0; it < nk; ++it) {
        int cur = it & 1;
        if (it + 1 < nk) STAGE(cur ^ 1, (it + 1) << 6);
#pragma unroll
        for (int kk = 0; kk < 2; kk++) {
            int ch = ((kk << 2) + g);
            bf16x8 af[4], bfr[2];
#pragma unroll
            for (int m = 0; m < 4; m++)
                af[m] = *(const bf16x8*)
                    &As[cur][(wr * 64 + m * 16 + c) * 64 + ((ch ^ cs) << 3)];
#pragma unroll
            for (int n = 0; n < 2; n++)
                bfr[n] = *(const bf16x8*)
                    &Bs[cur][(wc * 32 + n * 16 + c) * 64 + ((ch ^ cs) << 3)];
#pragma unroll
            for (int m = 0; m < 4; m++)
#pragma unroll
                for (int n = 0; n < 2; n++)
                    acc[m][n] = mfma16(af[m], bfr[n], acc[m][n]);
        }
        __syncthreads();
    }

    float bv[2] = {0.f, 0.f};
    if (BIAS) {
#pragma unroll
        for (int n = 0; n < 2; n++) bv[n] = bias[n0 + wc * 32 + n * 16 + c];
    }
    float* Cf = (float*)Cv;
    bf16* Cb = (bf16*)Cv;
#pragma unroll
    for (int m = 0; m < 4; m++)
#pragma unroll
        for (int n = 0; n < 2; n++)
#pragma unroll
            for (int j = 0; j < 4; j++) {
                long row = row0 + wr * 64 + m * 16 + g * 4 + j;
                int col = n0 + wc * 32 + n * 16 + c;
                float v = acc[m][n][j];
                if (BIAS) v += bv[n];
                if (RELU) v = fmaxf(v, 0.f);
                if (OUT_BF16) Cb[row * N + col] = (bf16)v;
                else Cf[row * N + col] = v;
            }
}

// ------------- 128x128 MFMA GEMM core (double-buffered, BK=32) -------------
template<int OUT_BF16>
__device__ inline void gemm128_body(
    const bf16* __restrict__ Ab, const bf16* __restrict__ Bb,
    void* __restrict__ Cv, int N, int K, float scale,
    long row0, int n0)
{
    __shared__ bf16 As[2][4096];
    __shared__ bf16 Bs[2][4096];
    int tid = threadIdx.x;
    int lane = tid & 63, w = tid >> 6;
    int wr = w >> 1, wc = w & 1;
    int g = lane >> 4, c = lane & 15;

    f32x4 acc[4][4];
#pragma unroll
    for (int m = 0; m < 4; m++)
#pragma unroll
        for (int n = 0; n < 4; n++) acc[m][n] = (f32x4){0.f, 0.f, 0.f, 0.f};

    int lr4 = lane >> 2, lc8 = (lane & 3) * 8;
    auto STAGE = [&](int buf, int k0) {
        const bf16* ga = Ab + (row0 + w * 16 + lr4) * (long)K + k0 + lc8;
        gload16(ga, &As[buf][(w * 16) * 32]);
        gload16(ga + (long)64 * K, &As[buf][(w * 16 + 64) * 32]);
        const bf16* gb = Bb + (long)(n0 + w * 16 + lr4) * K + k0 + lc8;
        gload16(gb, &Bs[buf][(w * 16) * 32]);
        gload16(gb + (long)64 * K, &Bs[buf][(w * 16 + 64) * 32]);
    };

    STAGE(0, 0);
    __syncthreads();
    int nk = K >> 5;
    for (int it = 0; it < nk; ++it) {
        int cur = it & 1;
        if (it + 1 < nk) STAGE(cur ^ 1, (it + 1) << 5);
        bf16x8 af[4], bfr[4];
#pragma unroll
        for (int m = 0; m < 4; m++)
            af[m] = *(const bf16x8*)&As[cur][(wr * 64 + m * 16 + c) * 32 + g * 8];
#pragma unroll
        for (int n = 0; n < 4; n++)
            bfr[n] = *(const bf16x8*)&Bs[cur][(wc * 64 + n * 16 + c) * 32 + g * 8];
#pragma unroll
        for (int m = 0; m < 4; m++)
#pragma unroll
            for (int n = 0; n < 4; n++)
                acc[m][n] = mfma16(af[m], bfr[n], acc[m][n]);
        __syncthreads();
    }

    float* Cf = (float*)Cv;
    bf16* Cb = (bf16*)Cv;
#pragma unroll
    for (int m = 0; m < 4; m++)
#pragma unroll
        for (int n = 0; n < 4; n++)
#pragma unroll
            for (int j = 0; j < 4; j++) {
                long row = row0 + wr * 64 + m * 16 + g * 4 + j;
                int col = n0 + wc * 64 + n * 16 + c;
                float v = acc[m][n][j] * scale;
                if (OUT_BF16) Cb[row * N + col] = (bf16)v;
                else Cf[row * N + col] = v;
            }
}

// batched final-scores GEMM (fp32 out, scaled)
__global__ __launch_bounds__(256) void mfma_gemm128(
    const bf16* __restrict__ A, const bf16* __restrict__ Bt,
    float* __restrict__ Cv, int N, int K, float scale,
    long sA, long sB, long sC)
{
    long z = blockIdx.z;
    gemm128_body<0>(A + z * sA, Bt + z * sB, Cv + z * sC, N, K, scale,
                    (long)blockIdx.y * 128, blockIdx.x * 128);
}

// Q/K/V (z=3) or qf/kf (z=2) batched projections, 128x128 tiles.
__global__ __launch_bounds__(256) void qkv_gemm(
    const bf16* __restrict__ Ah, const bf16* __restrict__ Ax,
    const bf16* __restrict__ B0, const bf16* __restrict__ B1,
    const bf16* __restrict__ B2,
    bf16* __restrict__ C0, bf16* __restrict__ C1, bf16* __restrict__ C2,
    float scale0)
{
    int z = blockIdx.z;
    if (z == 0 && blockIdx.y >= 32) return;
    const bf16* A = z ? Ax : Ah;
    const bf16* Bt = (z == 0) ? B0 : (z == 1 ? B1 : B2);
    bf16* C = (z == 0) ? C0 : (z == 1 ? C1 : C2);
    gemm128_body<1>(A, Bt, C, 512, 512, z == 0 ? scale0 : 1.f,
                    (long)blockIdx.y * 128, blockIdx.x * 128);
}

// ------------- MFMA flash attention: 8 waves x 16 q = 128 q/block -------------
// Grid 512 flat = (8 qb, 32 bh, 2 sp) XCD-chunked. Q pre-scaled 0.125*log2e.
// Lane-local l_r partials (reduced once at end); cheap mask extract.
__global__ __launch_bounds__(512, 4) void attn_mfma(
    const bf16* __restrict__ QP, const bf16* __restrict__ KP,
    const bf16* __restrict__ Vt, const unsigned* __restrict__ bits,
    bf16* __restrict__ Opart, float* __restrict__ Mpart,
    float* __restrict__ Lpart)
{
    __shared__ bf16 Kls[2][4096];      // [buf][64 keys x 64 d], swizzled
    __shared__ bf16 Vls[2][4096];      // [buf][64 d x 64 keys], swizzled
    __shared__ bf16 Pl[8][1024];       // per-wave P [q=c][64 keys], XOR-swizzled

    int tid = threadIdx.x;
    int lane = tid & 63, wv = tid >> 6;   // 8 waves
    int g = lane >> 4, c = lane & 15;

    int flat = blockIdx.x;                          // 512 blocks
    int logical = (flat & 7) * 64 + (flat >> 3);    // XCD-chunked
    int bh = logical >> 4;
    int rr = logical & 15;
    int sp = rr >> 3;
    int q0 = (rr & 7) * 128 + wv * 16;
    int b = bh >> 3;

    long qrow0 = (long)bh * 1024 + q0;
    long krow0 = (long)bh * 2048 + (long)sp * 1024;
    const bf16* vtb = Vt + (long)bh * 131072 + (long)sp * 1024;
    const unsigned* bitrow = bits + ((long)b * 1024 + q0 + c) * 64 + sp * 32;

    int lr = lane >> 3, lc = lane & 7;
    int scol = (lc ^ lr) * 8;                       // pre-swizzled src col
    int cs = c & 7;

    bf16x8 qa[2];
#pragma unroll
    for (int hh = 0; hh < 2; hh++)
        qa[hh] = *(const bf16x8*)(QP + (qrow0 + c) * 64 + hh * 32 + g * 8);

    f32x4 o_acc[4];
#pragma unroll
    for (int ot = 0; ot < 4; ot++) o_acc[ot] = (f32x4){0.f, 0.f, 0.f, 0.f};
    float m_r = -1e30f, l_r = 0.f;     // l_r lane-local (exact: fct row-uniform)

    {
        const bf16* sk = KP + (krow0 + wv * 8 + lr) * 64 + scol;
        gload16(sk, &Kls[0][(wv * 8) * 64]);
        const bf16* sv = vtb + (long)(wv * 8 + lr) * 2048 + scol;
        gload16(sv, &Vls[0][(wv * 8) * 64]);
    }
    uint2 wp_nxt = *(const uint2*)(bitrow);
    __syncthreads();

    const int NT = LKK / KSPLIT / 64;   // 16
    for (int kt = 0; kt < NT; kt++) {
        int cur = kt & 1;
        if (kt + 1 < NT) {
            int kn = (kt + 1) * 64;
            const bf16* sk = KP + (krow0 + kn + wv * 8 + lr) * 64 + scol;
            gload16(sk, &Kls[cur ^ 1][(wv * 8) * 64]);
            const bf16* sv = vtb + (long)(wv * 8 + lr) * 2048 + kn + scol;
            gload16(sv, &Vls[cur ^ 1][(wv * 8) * 64]);
        }
        uint2 wp = wp_nxt;
        if (kt + 1 < NT) wp_nxt = *(const uint2*)(bitrow + (kt + 1) * 2);

        // S^T = K Q^T from LDS (swizzled read); already log2-domain
        const char* kls = (const char*)&Kls[cur][0];
        f32x4 s[4];
        __builtin_amdgcn_s_setprio(1);
#pragma unroll
        for (int mt = 0; mt < 4; mt++) {
            bf16x8 ka0 = *(const bf16x8*)(kls + (mt * 16 + c) * 128 + ((g ^ cs) << 4));
            bf16x8 ka1 = *(const bf16x8*)(kls + (mt * 16 + c) * 128 + (((4 + g) ^ cs) << 4));
            s[mt] = mfma16(ka0, qa[0], (f32x4){0.f, 0.f, 0.f, 0.f});
            s[mt] = mfma16(ka1, qa[1], s[mt]);
        }
        __builtin_amdgcn_s_setprio(0);

        // mask: one runtime shift per mt, then constant-shift bit tests
#pragma unroll
        for (int mt = 0; mt < 4; mt++) {
            unsigned wm = ((mt < 2) ? wp.x : wp.y) >> ((mt & 1) * 16 + 4 * g);
#pragma unroll
            for (int j = 0; j < 4; j++)
                if ((wm >> j) & 1) s[mt][j] = -1e30f;
        }

        // online softmax (log2 domain): conditional row-max + defer-max
        float mxl = -1e30f;
#pragma unroll
        for (int mt = 0; mt < 4; mt++)
            mxl = fmaxf(mxl, fmaxf(fmaxf(s[mt][0], s[mt][1]),
                                   fmaxf(s[mt][2], s[mt][3])));

        float fct = 1.f;
        if (__any(mxl > m_r + 11.5415f)) {
            float mx = fmaxf(mxl, __shfl_xor(mxl, 16, 64));
            mx = fmaxf(mx, __shfl_xor(mx, 32, 64));
            float mnew = fmaxf(m_r, mx);
            fct = fexp2(m_r - mnew);
            m_r = mnew;
            float fq[4];
#pragma unroll
            for (int j = 0; j < 4; j++)
                fq[j] = __shfl(fct, (lane & 48) | (4 * g + j), 64);
#pragma unroll
            for (int ot = 0; ot < 4; ot++)
#pragma unroll
                for (int j = 0; j < 4; j++) o_acc[ot][j] *= fq[j];
        }

        float sum = 0.f;
#pragma unroll
        for (int mt = 0; mt < 4; mt++)
#pragma unroll
            for (int j = 0; j < 4; j++) {
                float p = fexp2(s[mt][j] - m_r);
                s[mt][j] = p;
                sum += p;
            }
        l_r = l_r * fct + sum;   // lane-local; reduced once at end

        // P -> per-wave LDS, XOR-swizzled
        char* plb = (char*)&Pl[wv][0];
#pragma unroll
        for (int mt = 0; mt < 4; mt++) {
            bf16x4 pk;
#pragma unroll
            for (int j = 0; j < 4; j++) pk[j] = (bf16)s[mt][j];
            int wch = (mt * 2 + (g >> 1)) ^ cs;
            *(bf16x4*)(plb + c * 128 + (wch << 4) + (g & 1) * 8) = pk;
        }

        // PV
        const char* vls = (const char*)&Vls[cur][0];
        __builtin_amdgcn_s_setprio(1);
#pragma unroll
        for (int kh = 0; kh < 2; kh++) {
            bf16x8 pa = *(const bf16x8*)(plb + c * 128 + ((((kh << 2) + g) ^ cs) << 4));
#pragma unroll
            for (int ot = 0; ot < 4; ot++) {
                bf16x8 vbf = *(const bf16x8*)
                    (vls + (ot * 16 + c) * 128 + ((((kh << 2) + g) ^ cs) << 4));
                o_acc[ot] = mfma16(pa, vbf, o_acc[ot]);
            }
        }
        __builtin_amdgcn_s_setprio(0);
        __syncthreads();
    }

    // final l_r row-reduction
    l_r += __shfl_xor(l_r, 16, 64);
    l_r += __shfl_xor(l_r, 32, 64);

    long ob = ((long)sp * NROWS + qrow0) * 64;
#pragma unroll
    for (int ot = 0; ot < 4; ot++)
#pragma unroll
        for (int j = 0; j < 4; j++)
            Opart[ob + (long)(4 * g + j) * 64 + ot * 16 + c] = (bf16)o_acc[ot][j];
    if (g == 0) {
        Mpart[(long)sp * NROWS + qrow0 + c] = m_r;
        Lpart[(long)sp * NROWS + qrow0 + c] = l_r;
    }
}

// ------------- combine k-split partials (vectorized bf16x4) -------------
__global__ __launch_bounds__(256) void attn_combine(
    const bf16* __restrict__ Op, const float* __restrict__ Mp,
    const float* __restrict__ Lp, bf16* __restrict__ O)
{
    long idx4 = ((long)blockIdx.x * 256 + threadIdx.x) * 4;
    long row = idx4 >> 6;
    float m0 = Mp[row], m1 = Mp[NROWS + row];
    float l0 = Lp[row], l1 = Lp[NROWS + row];
    float mm = fmaxf(m0, m1);
    float e0 = fexp2(m0 - mm), e1 = fexp2(m1 - mm);
    float inv = 1.f / (l0 * e0 + l1 * e1);
    bf16x4 a = *(const bf16x4*)(Op + idx4);
    bf16x4 bvv = *(const bf16x4*)(Op + (long)NROWS * 64 + idx4);
    bf16x4 o;
#pragma unroll
    for (int j = 0; j < 4; j++)
        o[j] = (bf16)(((float)a[j] * e0 + (float)bvv[j] * e1) * inv);
    *(bf16x4*)(O + idx4) = o;
}

// ------------- LN(residual), two-input -------------
__global__ __launch_bounds__(256) void ln_kernel(
    const float* __restrict__ res, const float* __restrict__ y,
    const float* __restrict__ g, const float* __restrict__ bb,
    float* __restrict__ outf, bf16* __restrict__ outb)
{
    int wave = threadIdx.x >> 6, lane = threadIdx.x & 63;
    long row = (long)blockIdx.x * 4 + wave;
    const float* rp = res + row * D_MODEL;
    const float* yp = y + row * D_MODEL;
    float v[8];
    float s = 0.f, sq = 0.f;
#pragma unroll
    for (int j = 0; j < 8; j++) {
        int col = lane + 64 * j;
        v[j] = rp[col] + yp[col];
        s += v[j]; sq += v[j] * v[j];
    }
#pragma unroll
    for (int o = 32; o > 0; o >>= 1) {
        s += __shfl_down(s, o, 64);
        sq += __shfl_down(sq, o, 64);
    }
    s = __shfl(s, 0, 64);
    sq = __shfl(sq, 0, 64);
    float mean = s * (1.f / 512.f);
    float var = sq * (1.f / 512.f) - mean * mean;
    float rstd = rsqrtf(fmaxf(var, 0.f) + 1e-5f);
    float* opf = outf + row * D_MODEL;
    bf16* opb = outb + row * D_MODEL;
#pragma unroll
    for (int j = 0; j < 8; j++) {
        int col = lane + 64 * j;
        float o = (v[j] - mean) * rstd * g[col] + bb[col];
        opf[col] = o;
        opb[col] = (bf16)o;
    }
}

extern "C" void kernel_launch(void* const* d_in, const int* in_sizes, int n_in,
                              void* d_out, int out_size, void* d_ws, size_t ws_size,
                              hipStream_t stream)
{
    const float* x    = (const float*)d_in[0];
    const float* hin  = (const float*)d_in[1];
    const int*   mask = (const int*)d_in[2];
    const float* wq   = (const float*)d_in[3];
    const float* wk   = (const float*)d_in[4];
    const float* wv   = (const float*)d_in[5];
    const float* wo   = (const float*)d_in[6];
    const float* ffw1 = (const float*)d_in[7];
    const float* ffb1 = (const float*)d_in[8];
    const float* ffw2 = (const float*)d_in[9];
    const float* ffb2 = (const float*)d_in[10];
    const float* g1   = (const float*)d_in[11];
    const float* be1  = (const float*)d_in[12];
    const float* g2   = (const float*)d_in[13];
    const float* be2  = (const float*)d_in[14];
    const float* out_wq = (const float*)d_in[15];
    const float* out_wk = (const float*)d_in[16];
    float* out = (float*)d_out;

    const long NQ = (long)BB * LQ;   // 4096
    const long NK = (long)BB * LKK;  // 8192

    // workspace layout (bytes). SH region time-shares y_f / V-plane / Opart.
    char* W = (char*)d_ws;
    float* h_f  = (float*)(W);                      // 8 MB
    char*  SH   = W + 8388608;                      // 8 MB shared region
    float* y_f  = (float*)SH;
    bf16*  v_pl = (bf16*)SH;
    bf16*  opart= (bf16*)SH;
    bf16*  h_b  = (bf16*)(W + 16777216);            // 4 MB
    bf16*  x_b  = (bf16*)(W + 20971520);            // 8 MB
    bf16*  q_b  = (bf16*)(W + 29360128);            // 4 MB
    bf16*  a_b  = (bf16*)(W + 33554432);            // 4 MB
    bf16*  k_pl = (bf16*)(W + 37748736);            // 8 MB
    bf16*  vt   = (bf16*)(W + 46137344);            // 8 MB
    bf16*  wts  = (bf16*)(W + 54525952);            // 19 matrices (9.5 MB)
    bf16*  wtOQ = wts + 19 * WSZC;                  // +0.5 MB
    unsigned* mb = (unsigned*)(W + 65011712);       // 1 MB
    float* Mpart = (float*)(W + 66060288);          // 256 KB
    float* Lpart = (float*)(W + 66322432);          // 256 KB

    dim3 blk(256);
    dim3 blk512(512);

    // preprocessing
    cast_kernel<<<dim3((NK * D_MODEL / 4 + 255) / 256), blk, 0, stream>>>(x, x_b, NK * D_MODEL);
    cast_dual<<<dim3((NQ * D_MODEL / 4 + 255) / 256), blk, 0, stream>>>(hin, h_f, h_b, NQ * D_MODEL);
    tcast_all<<<dim3(16, 16, 20), blk, 0, stream>>>(
        wq, wo, ffw1, ffw2, wk, wv, out_wq, out_wk, wts, wtOQ);
    maskbits_kernel<<<dim3(32768), blk, 0, stream>>>(mask, mb);

    dim3 gq(8, 32, 1);           // 4096 x 512 (128x64, BK=64)
    dim3 gqkv(4, 64, 3);         // z: Q(4096) / K(8192) / V(8192), 128x128 BK=32
    dim3 gvt(32, 32);
    dim3 ga(512);                // flat, XCD-swizzled inside; 512-thread blocks
    dim3 gc(NROWS * 64 / 1024);  // vectorized combine: 2048 blocks

    const float C2 = 0.1803368801111243f;   // 0.125 * log2(e)

    for (int i = 0; i < NL; i++) {
        qkv_gemm<<<gqkv, blk, 0, stream>>>(h_b, x_b,
            wts + i * WSZC, wts + (12 + 2 * i) * WSZC, wts + (13 + 2 * i) * WSZC,
            q_b, k_pl, v_pl, C2);
        vtrans_kernel<<<gvt, blk, 0, stream>>>(v_pl, vt);

        attn_mfma<<<ga, blk512, 0, stream>>>(q_b, k_pl, vt, mb, opart, Mpart, Lpart);
        attn_combine<<<gc, blk, 0, stream>>>(opart, Mpart, Lpart, a_b);

        mfma_gemm<0,0,0><<<gq, blk, 0, stream>>>(a_b, wts + (3 + i) * WSZC,
            nullptr, y_f, 512, 512);
        ln_kernel<<<dim3(NQ / 4), blk, 0, stream>>>(h_f, y_f,
            g1 + i * D_MODEL, be1 + i * D_MODEL, h_f, h_b);

        mfma_gemm<1,1,1><<<gq, blk, 0, stream>>>(h_b, wts + (6 + i) * WSZC,
            ffb1 + i * D_MODEL, q_b, 512, 512);
        mfma_gemm<1,0,0><<<gq, blk, 0, stream>>>(q_b, wts + (9 + i) * WSZC,
            ffb2 + i * D_MODEL, y_f, 512, 512);
        ln_kernel<<<dim3(NQ / 4), blk, 0, stream>>>(h_f, y_f,
            g2 + i * D_MODEL, be2 + i * D_MODEL, h_f, h_b);
    }

    // final: qf = h@out_wq (z=0, unscaled), kf = x@out_wk (z=1)
    dim3 gqk(4, 64, 2);
    qkv_gemm<<<gqk, blk, 0, stream>>>(h_b, x_b,
        wtOQ, wts + 18 * WSZC, wts + 18 * WSZC, q_b, k_pl, k_pl, 1.f);

    dim3 gf(LKK / 128, LQ / 128, BB);
    mfma_gemm128<<<gf, blk, 0, stream>>>(q_b, k_pl, out,
        LKK, 512, 0.04419417382415922f,
        (long)LQ * 512, (long)LKK * 512, (long)LQ * LKK);
}